// Round 4
// baseline (2779.744 us; speedup 1.0000x reference)
//
#include <hip/hip_runtime.h>
#include <hip/hip_bf16.h>
#include <stdint.h>

// Problem constants
#define B_ 128
#define T_ 40
#define E_ 512
#define H_ 512
#define G_ 2048   // 4*H gates
#define V_ 10000
#define F_ 2048   // fc_feat

typedef __attribute__((ext_vector_type(8))) short short8;
typedef __attribute__((ext_vector_type(4))) short short4v;
typedef __attribute__((ext_vector_type(4))) float f32x4;

__device__ __forceinline__ float bf2f(short s) {
    unsigned u = ((unsigned)(unsigned short)s) << 16;
    float f;
    __builtin_memcpy(&f, &u, 4);
    return f;
}
__device__ __forceinline__ short f2bf(float f) {
    unsigned u;
    __builtin_memcpy(&u, &f, 4);
    u = (u + 0x7fffu + ((u >> 16) & 1u)) >> 16;
    return (short)u;
}
__device__ __forceinline__ float sigf(float x) { return 1.f / (1.f + __expf(-x)); }
__device__ __forceinline__ float tanh_fast(float x) { return 2.f / (1.f + __expf(-2.f * x)) - 1.f; }

// ---------------------------------------------------------------------------
// f32 -> bf16 convert, vectorized: 2x float4 load -> short8 store per thread.
__global__ __launch_bounds__(256) void convert_k(const float* __restrict__ src,
                                                 short* __restrict__ dst, int n) {
    int stride = gridDim.x * blockDim.x;
    int nv = n >> 3;
    for (int i = blockIdx.x * blockDim.x + threadIdx.x; i < nv; i += stride) {
        f32x4 a = ((const f32x4*)src)[2 * i];
        f32x4 b = ((const f32x4*)src)[2 * i + 1];
        short8 o;
        o[0] = f2bf(a[0]); o[1] = f2bf(a[1]); o[2] = f2bf(a[2]); o[3] = f2bf(a[3]);
        o[4] = f2bf(b[0]); o[5] = f2bf(b[1]); o[6] = f2bf(b[2]); o[7] = f2bf(b[3]);
        ((short8*)dst)[i] = o;
    }
}

// combined biases: bias = bih + bhh, for both cells
__global__ __launch_bounds__(256) void bias2_k(const float* __restrict__ ab, const float* __restrict__ ah,
                                               float* __restrict__ oa,
                                               const float* __restrict__ fb, const float* __restrict__ fh,
                                               float* __restrict__ of) {
    int t = blockIdx.x * 256 + threadIdx.x;
    if (t < G_) oa[t] = ab[t] + ah[t];
    else if (t < 2 * G_) { int u = t - G_; of[u] = fb[u] + fh[u]; }
}

// ---------------------------------------------------------------------------
// Gather word embeddings into bf16 GEMM input rows (vectorized float4->short4).
__global__ __launch_bounds__(256) void gather_k(const int* __restrict__ word_idx,
                                                const int* __restrict__ father_idx,
                                                const float* __restrict__ embed,
                                                short* __restrict__ XaIn,
                                                short* __restrict__ XfIn) {
    int rr = blockIdx.x;            // rr = b*40 + i
    int i = rr % T_;
    int b = rr / T_;
    int tid = threadIdx.x;
    if (tid < 128) {
        if (i >= 1) {
            int fa = father_idx[rr];
            int wa = word_idx[b * T_ + fa];
            f32x4 v = ((const f32x4*)(embed + (size_t)wa * E_))[tid];
            short4v o = {f2bf(v[0]), f2bf(v[1]), f2bf(v[2]), f2bf(v[3])};
            ((short4v*)(XaIn + (size_t)rr * E_))[tid] = o;
        }
    } else {
        int t = tid - 128;
        bool zf = (i == 0) || (((i - 1) % 3) == 0);
        short4v o = {0, 0, 0, 0};
        if (!zf) {
            int wp = word_idx[rr - 1];  // word_idx[b][i-1]
            f32x4 v = ((const f32x4*)(embed + (size_t)wp * E_))[t];
            o[0] = f2bf(v[0]); o[1] = f2bf(v[1]); o[2] = f2bf(v[2]); o[3] = f2bf(v[3]);
        }
        ((short4v*)(XfIn + (size_t)rr * E_))[t] = o;
    }
}

// ---------------------------------------------------------------------------
// Generic MFMA GEMM: C[M,N] = A[M,K](bf16) * B[N,K]^T(bf16) + bias[N]
template <int OUT_BF16, int DO_TANH>
__global__ __launch_bounds__(256) void gemm_bt(const short* __restrict__ A, int lda,
                                               const short* __restrict__ B,
                                               const float* __restrict__ bias,
                                               void* __restrict__ C, int ldc,
                                               int M, int N, int K) {
    int wave = threadIdx.x >> 6, lane = threadIdx.x & 63;
    int row0 = blockIdx.y * 128 + (wave >> 1) * 64;
    int col0 = blockIdx.x * 128 + (wave & 1) * 64;
    int r = lane & 15, kg = lane >> 4;
    short8 bz = {0, 0, 0, 0, 0, 0, 0, 0};
    bool cv[4];
    const short *Ab[4], *Bb[4];
#pragma unroll
    for (int t = 0; t < 4; t++) {
        cv[t] = (col0 + t * 16) < N;
        Ab[t] = A + (size_t)(row0 + t * 16 + r) * lda + kg * 8;
        Bb[t] = B + (size_t)(cv[t] ? (col0 + t * 16 + r) : 0) * K + kg * 8;
    }
    f32x4 acc[4][4] = {};
    for (int k0 = 0; k0 < K; k0 += 32) {
        short8 af[4], bf[4];
#pragma unroll
        for (int t = 0; t < 4; t++) af[t] = *(const short8*)(Ab[t] + k0);
#pragma unroll
        for (int t = 0; t < 4; t++) bf[t] = cv[t] ? *(const short8*)(Bb[t] + k0) : bz;
#pragma unroll
        for (int mt = 0; mt < 4; mt++)
#pragma unroll
            for (int nt = 0; nt < 4; nt++)
                acc[mt][nt] = __builtin_amdgcn_mfma_f32_16x16x32_bf16(af[mt], bf[nt], acc[mt][nt], 0, 0, 0);
    }
#pragma unroll
    for (int nt = 0; nt < 4; nt++) {
        if (!cv[nt]) continue;
        int col = col0 + nt * 16 + r;
        float bs = bias ? bias[col] : 0.f;
#pragma unroll
        for (int mt = 0; mt < 4; mt++) {
#pragma unroll
            for (int j = 0; j < 4; j++) {
                int row = row0 + mt * 16 + kg * 4 + j;
                float v = acc[mt][nt][j] + bs;
                if (DO_TANH) v = tanh_fast(v);
                if (OUT_BF16) ((short*)C)[(size_t)row * ldc + col] = f2bf(v);
                else          ((float*)C)[(size_t)row * ldc + col] = v;
            }
        }
    }
}

// ---------------------------------------------------------------------------
// Persistent recurrence, register-resident weights.
// 256 blocks = 2 cells x 8 row-groups(16 rows) x 16 unit-groups(32 units).
// 4 waves/block, wave = gate. Each wave holds its weight slice
// (32 cols x K=512 = 128 VGPR) in registers for all 40 steps.
// Per step: 16 independent A-frag loads + 32 MFMA, gates swapped via LDS,
// then LSTM elementwise. Cross-block H_all ordering via a minimal
// sense-reversing grid barrier (bar[0]=cnt, bar[1]=step sense).
__global__ __launch_bounds__(256, 1) void steps2_k(const short* __restrict__ XaP,
                                                   const short* __restrict__ XfP,
                                                   const short* __restrict__ a_whh_h,
                                                   const short* __restrict__ f_whh_h,
                                                   short* __restrict__ H_all,
                                                   float* __restrict__ cS,
                                                   float* __restrict__ bcS,
                                                   const int* __restrict__ father_idx,
                                                   int* __restrict__ bar) {
    int blk = blockIdx.x;
    int cell = blk >> 7;          // 0..1
    int rh = (blk >> 4) & 7;      // 8 row groups of 16 rows
    int ug = blk & 15;            // 16 unit groups of 32 units
    int row0 = rh * 16;
    int n0 = ug * 32;
    int g = threadIdx.x >> 6;     // wave = gate (i,f,g,o)
    int lane = threadIdx.x & 63;
    int r = lane & 15, kg = lane >> 4;
    __shared__ float lds_g[4][16][33];

    // Load loop-invariant weight slice into registers (32 cols x 512 K).
    const short* Wh = cell ? f_whh_h : a_whh_h;
    short8 bw[16][2];
#pragma unroll
    for (int ks = 0; ks < 16; ks++)
#pragma unroll
        for (int nt = 0; nt < 2; nt++)
            bw[ks][nt] = *(const short8*)(Wh + (size_t)(g * H_ + n0 + nt * 16 + r) * H_ + ks * 32 + kg * 8);

    const short* XP = cell ? XfP : XaP;

    for (int i = 0; i < T_; i++) {
        int reset = (i == 0) || (((i - 1) % 3) == 0);      // fraternal reset
        int skip = (i == 0) || (cell == 1 && reset);       // skip h-GEMM
        if (!skip) {
            int b = row0 + r;
            int si = (cell == 0) ? father_idx[b * T_ + i] : (i - 1);
            const short* Arow = H_all + (((size_t)(b * T_ + si)) * 2 + cell) * H_ + kg * 8;
            short8 af[16];
#pragma unroll
            for (int ks = 0; ks < 16; ks++) af[ks] = *(const short8*)(Arow + ks * 32);
            f32x4 acc[2] = {};
#pragma unroll
            for (int ks = 0; ks < 16; ks++) {
                acc[0] = __builtin_amdgcn_mfma_f32_16x16x32_bf16(af[ks], bw[ks][0], acc[0], 0, 0, 0);
                acc[1] = __builtin_amdgcn_mfma_f32_16x16x32_bf16(af[ks], bw[ks][1], acc[1], 0, 0, 0);
            }
#pragma unroll
            for (int nt = 0; nt < 2; nt++)
#pragma unroll
                for (int j = 0; j < 4; j++)
                    lds_g[g][kg * 4 + j][nt * 16 + r] = acc[nt][j];
        }
        __syncthreads();
        // elementwise: 16 rows x 32 units = 512 elems, 2 per thread
        for (int e = threadIdx.x; e < 512; e += 256) {
            int br = e >> 5;
            int b = row0 + br;
            int nn = e & 31;
            int n = n0 + nn;
            size_t xbase = ((size_t)(b * T_ + i)) * G_ + n;
            float gi = bf2f(XP[xbase + 0 * H_]);
            float gf = bf2f(XP[xbase + 1 * H_]);
            float gg = bf2f(XP[xbase + 2 * H_]);
            float go = bf2f(XP[xbase + 3 * H_]);
            if (!skip) {
                gi += lds_g[0][br][nn];
                gf += lds_g[1][br][nn];
                gg += lds_g[2][br][nn];
                go += lds_g[3][br][nn];
            }
            float cprev;
            if (cell == 0) {
                if (i == 0) cprev = 0.f;
                else {
                    int pi = father_idx[b * T_ + i];
                    cprev = cS[((size_t)(b * T_ + pi)) * H_ + n];
                }
            } else {
                cprev = reset ? 0.f : bcS[((size_t)(b * T_ + (i - 1))) * H_ + n];
            }
            float c2 = sigf(gf) * cprev + sigf(gi) * tanh_fast(gg);
            float h2 = sigf(go) * tanh_fast(c2);
            if (cell == 0) cS[((size_t)(b * T_ + i)) * H_ + n] = c2;
            else           bcS[((size_t)(b * T_ + i)) * H_ + n] = c2;
            H_all[(((size_t)(b * T_ + i)) * 2 + cell) * H_ + n] = f2bf(h2);
        }
        // ---- grid barrier: publish H_all, then wait for step sense i+1 ----
        __threadfence();
        __syncthreads();
        if (threadIdx.x == 0) {
            if (atomicAdd(&bar[0], 1) == 255) {
                atomicExch(&bar[0], 0);   // reset BEFORE release (no re-arrival until release)
                __hip_atomic_store(&bar[1], i + 1, __ATOMIC_RELEASE, __HIP_MEMORY_SCOPE_AGENT);
            } else {
                while (__hip_atomic_load(&bar[1], __ATOMIC_ACQUIRE, __HIP_MEMORY_SCOPE_AGENT) <= i)
                    __builtin_amdgcn_s_sleep(2);
            }
            __threadfence();   // acquire for subsequent plain loads (incl. last arriver)
        }
        __syncthreads();
    }
}

// ---------------------------------------------------------------------------
// In-place row log-softmax over V=10000, one block per row.
__global__ __launch_bounds__(256) void softmax_k(float* __restrict__ out) {
    __shared__ float buf[V_];
    __shared__ float red[4];
    int r = blockIdx.x;
    float* row = out + (size_t)r * V_;
    int tid = threadIdx.x;
    float lmax = -1e30f;
    for (int t = tid; t < V_; t += 256) {
        float v = row[t];
        buf[t] = v;
        lmax = fmaxf(lmax, v);
    }
#pragma unroll
    for (int o = 32; o; o >>= 1) lmax = fmaxf(lmax, __shfl_xor(lmax, o));
    if ((tid & 63) == 0) red[tid >> 6] = lmax;
    __syncthreads();
    float gmax = fmaxf(fmaxf(red[0], red[1]), fmaxf(red[2], red[3]));
    float ls = 0.f;
    for (int t = tid; t < V_; t += 256) ls += __expf(buf[t] - gmax);
#pragma unroll
    for (int o = 32; o; o >>= 1) ls += __shfl_xor(ls, o);
    __syncthreads();
    if ((tid & 63) == 0) red[tid >> 6] = ls;
    __syncthreads();
    float lse = gmax + __logf(red[0] + red[1] + red[2] + red[3]);
    for (int t = tid; t < V_; t += 256) row[t] = buf[t] - lse;
}

// ---------------------------------------------------------------------------
extern "C" void kernel_launch(void* const* d_in, const int* in_sizes, int n_in,
                              void* d_out, int out_size, void* d_ws, size_t ws_size,
                              hipStream_t stream) {
    const int* word_idx = (const int*)d_in[0];
    const int* father_idx = (const int*)d_in[1];
    const float* fc_feats = (const float*)d_in[2];
    const float* embed = (const float*)d_in[3];
    const float* fc_w = (const float*)d_in[4];
    const float* fc_b = (const float*)d_in[5];
    const float* a_wih = (const float*)d_in[6];
    const float* a_whh = (const float*)d_in[7];
    const float* a_bih = (const float*)d_in[8];
    const float* a_bhh = (const float*)d_in[9];
    const float* f_wih = (const float*)d_in[10];
    const float* f_whh = (const float*)d_in[11];
    const float* f_bih = (const float*)d_in[12];
    const float* f_bhh = (const float*)d_in[13];
    const float* pred_w = (const float*)d_in[14];
    const float* pred_b = (const float*)d_in[15];
    const float* logit_w = (const float*)d_in[16];
    const float* logit_b = (const float*)d_in[17];
    float* out = (float*)d_out;

    char* ws = (char*)d_ws;
    size_t off = 0;
    auto alloc = [&](size_t bytes) {
        void* p = ws + off;
        off += (bytes + 255) & ~(size_t)255;
        return p;
    };
    short* a_wih_h   = (short*)alloc((size_t)G_ * E_ * 2);
    short* f_wih_h   = (short*)alloc((size_t)G_ * E_ * 2);
    short* a_whh_h   = (short*)alloc((size_t)G_ * H_ * 2);
    short* f_whh_h   = (short*)alloc((size_t)G_ * H_ * 2);
    short* fc_w_h    = (short*)alloc((size_t)E_ * F_ * 2);
    short* pred_w_h  = (short*)alloc((size_t)H_ * 2 * H_ * 2);
    short* logit_w_h = (short*)alloc((size_t)V_ * H_ * 2);
    short* fc_feats_h= (short*)alloc((size_t)B_ * F_ * 2);
    float* bias_a    = (float*)alloc((size_t)G_ * 4);
    float* bias_f    = (float*)alloc((size_t)G_ * 4);
    short* XaIn      = (short*)alloc((size_t)B_ * T_ * E_ * 2);
    short* XfIn      = (short*)alloc((size_t)B_ * T_ * E_ * 2);
    short* XaP       = (short*)alloc((size_t)B_ * T_ * G_ * 2);
    short* XfP       = (short*)alloc((size_t)B_ * T_ * G_ * 2);
    short* H_all     = (short*)alloc((size_t)B_ * T_ * 2 * H_ * 2);
    float* cS        = (float*)alloc((size_t)B_ * T_ * H_ * 4);
    float* bcS       = (float*)alloc((size_t)B_ * T_ * H_ * 4);
    short* OUTb      = (short*)alloc((size_t)B_ * T_ * H_ * 2);
    int*   bar       = (int*)alloc(256);
    if (off > ws_size) return;  // ~109 MB needed; leaves output poisoned -> loud failure

    // Barrier state must be zero (ws is poisoned 0xAA before every call)
    hipMemsetAsync(bar, 0, 8, stream);

    // Phase 0: dtype converts + combined biases
    convert_k<<<512, 256, 0, stream>>>(a_wih, a_wih_h, G_ * E_);
    convert_k<<<512, 256, 0, stream>>>(f_wih, f_wih_h, G_ * E_);
    convert_k<<<512, 256, 0, stream>>>(a_whh, a_whh_h, G_ * H_);
    convert_k<<<512, 256, 0, stream>>>(f_whh, f_whh_h, G_ * H_);
    convert_k<<<512, 256, 0, stream>>>(fc_w, fc_w_h, E_ * F_);
    convert_k<<<512, 256, 0, stream>>>(pred_w, pred_w_h, H_ * 2 * H_);
    convert_k<<<1024, 256, 0, stream>>>(logit_w, logit_w_h, V_ * H_);
    convert_k<<<512, 256, 0, stream>>>(fc_feats, fc_feats_h, B_ * F_);
    bias2_k<<<16, 256, 0, stream>>>(a_bih, a_bhh, bias_a, f_bih, f_bhh, bias_f);

    // Phase 1: x_a0 = fc_feats @ fc_w.T + fc_b  -> bf16 rows (b, i=0) of XaIn
    gemm_bt<1, 0><<<dim3(4, 1), 256, 0, stream>>>(fc_feats_h, F_, fc_w_h, fc_b,
                                                  XaIn, T_ * E_, B_, E_, F_);
    // gather embeddings for all other rows
    gather_k<<<B_ * T_, 256, 0, stream>>>(word_idx, father_idx, embed, XaIn, XfIn);
    // batched input projections (bias folded in): XP = XIn @ wih.T + (bih+bhh)
    gemm_bt<1, 0><<<dim3(16, 40), 256, 0, stream>>>(XaIn, E_, a_wih_h, bias_a,
                                                    XaP, G_, B_ * T_, G_, E_);
    gemm_bt<1, 0><<<dim3(16, 40), 256, 0, stream>>>(XfIn, E_, f_wih_h, bias_f,
                                                    XfP, G_, B_ * T_, G_, E_);

    // Phase 2: persistent recurrence (cooperative launch guarantees co-residency)
    {
        void* args[] = {(void*)&XaP, (void*)&XfP, (void*)&a_whh_h, (void*)&f_whh_h,
                        (void*)&H_all, (void*)&cS, (void*)&bcS, (void*)&father_idx,
                        (void*)&bar};
        hipLaunchCooperativeKernel(reinterpret_cast<void*>(steps2_k), dim3(256), dim3(256),
                                   args, 0, stream);
    }

    // Phase 3: pred head, logits, log-softmax
    gemm_bt<1, 1><<<dim3(4, 40), 256, 0, stream>>>(H_all, 2 * H_, pred_w_h, pred_b,
                                                   OUTb, H_, B_ * T_, H_, 2 * H_);
    gemm_bt<0, 0><<<dim3(79, 40), 256, 0, stream>>>(OUTb, H_, logit_w_h, logit_b,
                                                    out, V_, B_ * T_, V_, H_);
    softmax_k<<<B_ * T_, 256, 0, stream>>>(out);
}

// Round 5
// 1165.769 us; speedup vs baseline: 2.3845x; 2.3845x over previous
//
#include <hip/hip_runtime.h>
#include <hip/hip_bf16.h>
#include <stdint.h>

// Problem constants
#define B_ 128
#define T_ 40
#define E_ 512
#define H_ 512
#define G_ 2048   // 4*H gates
#define V_ 10000
#define F_ 2048   // fc_feat

typedef __attribute__((ext_vector_type(8))) short short8;
typedef __attribute__((ext_vector_type(4))) short short4v;
typedef __attribute__((ext_vector_type(4))) float f32x4;

__device__ __forceinline__ float bf2f(short s) {
    unsigned u = ((unsigned)(unsigned short)s) << 16;
    float f;
    __builtin_memcpy(&f, &u, 4);
    return f;
}
__device__ __forceinline__ short f2bf(float f) {
    unsigned u;
    __builtin_memcpy(&u, &f, 4);
    u = (u + 0x7fffu + ((u >> 16) & 1u)) >> 16;
    return (short)u;
}
__device__ __forceinline__ float sigf(float x) { return 1.f / (1.f + __expf(-x)); }
__device__ __forceinline__ float tanh_fast(float x) { return 2.f / (1.f + __expf(-2.f * x)) - 1.f; }

// ---------------------------------------------------------------------------
// f32 -> bf16 convert, vectorized: 2x float4 load -> short8 store per thread.
__global__ __launch_bounds__(256) void convert_k(const float* __restrict__ src,
                                                 short* __restrict__ dst, int n) {
    int stride = gridDim.x * blockDim.x;
    int nv = n >> 3;
    for (int i = blockIdx.x * blockDim.x + threadIdx.x; i < nv; i += stride) {
        f32x4 a = ((const f32x4*)src)[2 * i];
        f32x4 b = ((const f32x4*)src)[2 * i + 1];
        short8 o;
        o[0] = f2bf(a[0]); o[1] = f2bf(a[1]); o[2] = f2bf(a[2]); o[3] = f2bf(a[3]);
        o[4] = f2bf(b[0]); o[5] = f2bf(b[1]); o[6] = f2bf(b[2]); o[7] = f2bf(b[3]);
        ((short8*)dst)[i] = o;
    }
}

// combined biases: bias = bih + bhh, for both cells
__global__ __launch_bounds__(256) void bias2_k(const float* __restrict__ ab, const float* __restrict__ ah,
                                               float* __restrict__ oa,
                                               const float* __restrict__ fb, const float* __restrict__ fh,
                                               float* __restrict__ of) {
    int t = blockIdx.x * 256 + threadIdx.x;
    if (t < G_) oa[t] = ab[t] + ah[t];
    else if (t < 2 * G_) { int u = t - G_; of[u] = fb[u] + fh[u]; }
}

// ---------------------------------------------------------------------------
// Gather word embeddings into bf16 GEMM input rows (vectorized float4->short4).
__global__ __launch_bounds__(256) void gather_k(const int* __restrict__ word_idx,
                                                const int* __restrict__ father_idx,
                                                const float* __restrict__ embed,
                                                short* __restrict__ XaIn,
                                                short* __restrict__ XfIn) {
    int rr = blockIdx.x;            // rr = b*40 + i
    int i = rr % T_;
    int b = rr / T_;
    int tid = threadIdx.x;
    if (tid < 128) {
        if (i >= 1) {
            int fa = father_idx[rr];
            int wa = word_idx[b * T_ + fa];
            f32x4 v = ((const f32x4*)(embed + (size_t)wa * E_))[tid];
            short4v o = {f2bf(v[0]), f2bf(v[1]), f2bf(v[2]), f2bf(v[3])};
            ((short4v*)(XaIn + (size_t)rr * E_))[tid] = o;
        }
    } else {
        int t = tid - 128;
        bool zf = (i == 0) || (((i - 1) % 3) == 0);
        short4v o = {0, 0, 0, 0};
        if (!zf) {
            int wp = word_idx[rr - 1];  // word_idx[b][i-1]
            f32x4 v = ((const f32x4*)(embed + (size_t)wp * E_))[t];
            o[0] = f2bf(v[0]); o[1] = f2bf(v[1]); o[2] = f2bf(v[2]); o[3] = f2bf(v[3]);
        }
        ((short4v*)(XfIn + (size_t)rr * E_))[t] = o;
    }
}

// ---------------------------------------------------------------------------
// Generic MFMA GEMM: C[M,N] = A[M,K](bf16) * B[N,K]^T(bf16) + bias[N]
template <int OUT_BF16, int DO_TANH>
__global__ __launch_bounds__(256) void gemm_bt(const short* __restrict__ A, int lda,
                                               const short* __restrict__ B,
                                               const float* __restrict__ bias,
                                               void* __restrict__ C, int ldc,
                                               int M, int N, int K) {
    int wave = threadIdx.x >> 6, lane = threadIdx.x & 63;
    int row0 = blockIdx.y * 128 + (wave >> 1) * 64;
    int col0 = blockIdx.x * 128 + (wave & 1) * 64;
    int r = lane & 15, kg = lane >> 4;
    short8 bz = {0, 0, 0, 0, 0, 0, 0, 0};
    bool cv[4];
    const short *Ab[4], *Bb[4];
#pragma unroll
    for (int t = 0; t < 4; t++) {
        cv[t] = (col0 + t * 16) < N;
        Ab[t] = A + (size_t)(row0 + t * 16 + r) * lda + kg * 8;
        Bb[t] = B + (size_t)(cv[t] ? (col0 + t * 16 + r) : 0) * K + kg * 8;
    }
    f32x4 acc[4][4] = {};
    for (int k0 = 0; k0 < K; k0 += 32) {
        short8 af[4], bf[4];
#pragma unroll
        for (int t = 0; t < 4; t++) af[t] = *(const short8*)(Ab[t] + k0);
#pragma unroll
        for (int t = 0; t < 4; t++) bf[t] = cv[t] ? *(const short8*)(Bb[t] + k0) : bz;
#pragma unroll
        for (int mt = 0; mt < 4; mt++)
#pragma unroll
            for (int nt = 0; nt < 4; nt++)
                acc[mt][nt] = __builtin_amdgcn_mfma_f32_16x16x32_bf16(af[mt], bf[nt], acc[mt][nt], 0, 0, 0);
    }
#pragma unroll
    for (int nt = 0; nt < 4; nt++) {
        if (!cv[nt]) continue;
        int col = col0 + nt * 16 + r;
        float bs = bias ? bias[col] : 0.f;
#pragma unroll
        for (int mt = 0; mt < 4; mt++) {
#pragma unroll
            for (int j = 0; j < 4; j++) {
                int row = row0 + mt * 16 + kg * 4 + j;
                float v = acc[mt][nt][j] + bs;
                if (DO_TANH) v = tanh_fast(v);
                if (OUT_BF16) ((short*)C)[(size_t)row * ldc + col] = f2bf(v);
                else          ((float*)C)[(size_t)row * ldc + col] = v;
            }
        }
    }
}

// ---------------------------------------------------------------------------
// One recurrence step, maximal parallelism, flat dependence graph.
// grid = 512 blocks: bit8 = cell, bits5-7 = row-group (16 rows),
// bits0-4 = unit-group (16 units). 4 waves/block, wave = gate.
// Per wave: 16x16xK=512 dot = 16 fully-unrolled independent A/B frag loads
// + 16 MFMAs. Gates swapped via LDS; elementwise 1 elem/thread.
// Inter-step ordering comes from the kernel-launch boundary.
__global__ __launch_bounds__(256) void step3_k(const short* __restrict__ XaP,
                                               const short* __restrict__ XfP,
                                               const short* __restrict__ a_whh_h,
                                               const short* __restrict__ f_whh_h,
                                               short* __restrict__ H_all,
                                               float* __restrict__ cS,
                                               float* __restrict__ bcS,
                                               const int* __restrict__ father_idx,
                                               int i, int reset) {
    int blk = blockIdx.x;
    int cell = blk >> 8;          // 0..1
    int rh = (blk >> 5) & 7;      // 8 row groups of 16 rows
    int ug = blk & 31;            // 32 unit groups of 16 units
    int row0 = rh * 16;
    int n0 = ug * 16;
    int g = threadIdx.x >> 6;     // wave = gate (i,f,g,o)
    int lane = threadIdx.x & 63;
    int r = lane & 15, kg = lane >> 4;
    __shared__ float lds_g[4][16][17];

    int skip = (i == 0) || (cell == 1 && reset);
    if (!skip) {
        int b = row0 + r;
        int si = (cell == 0) ? father_idx[b * T_ + i] : (i - 1);
        const short* Arow = H_all + (((size_t)(b * T_ + si)) * 2 + cell) * H_ + kg * 8;
        const short* Wh = cell ? f_whh_h : a_whh_h;
        const short* Brow = Wh + (size_t)(g * H_ + n0 + r) * H_ + kg * 8;
        short8 af[16], bf[16];
#pragma unroll
        for (int ks = 0; ks < 16; ks++) af[ks] = *(const short8*)(Arow + ks * 32);
#pragma unroll
        for (int ks = 0; ks < 16; ks++) bf[ks] = *(const short8*)(Brow + ks * 32);
        f32x4 acc = {};
#pragma unroll
        for (int ks = 0; ks < 16; ks++)
            acc = __builtin_amdgcn_mfma_f32_16x16x32_bf16(af[ks], bf[ks], acc, 0, 0, 0);
#pragma unroll
        for (int j = 0; j < 4; j++)
            lds_g[g][kg * 4 + j][r] = acc[j];
    }
    __syncthreads();
    // elementwise: 16 rows x 16 units, exactly 1 elem/thread
    int br = threadIdx.x >> 4;
    int nn = threadIdx.x & 15;
    int b = row0 + br;
    int n = n0 + nn;
    const short* XP = cell ? XfP : XaP;
    size_t xbase = ((size_t)(b * T_ + i)) * G_ + n;
    float gi = bf2f(XP[xbase + 0 * H_]);
    float gf = bf2f(XP[xbase + 1 * H_]);
    float gg = bf2f(XP[xbase + 2 * H_]);
    float go = bf2f(XP[xbase + 3 * H_]);
    if (!skip) {
        gi += lds_g[0][br][nn];
        gf += lds_g[1][br][nn];
        gg += lds_g[2][br][nn];
        go += lds_g[3][br][nn];
    }
    float cprev;
    if (cell == 0) {
        if (i == 0) cprev = 0.f;
        else {
            int pi = father_idx[b * T_ + i];
            cprev = cS[((size_t)(b * T_ + pi)) * H_ + n];
        }
    } else {
        cprev = reset ? 0.f : bcS[((size_t)(b * T_ + (i - 1))) * H_ + n];
    }
    float c2 = sigf(gf) * cprev + sigf(gi) * tanh_fast(gg);
    float h2 = sigf(go) * tanh_fast(c2);
    if (cell == 0) cS[((size_t)(b * T_ + i)) * H_ + n] = c2;
    else           bcS[((size_t)(b * T_ + i)) * H_ + n] = c2;
    H_all[(((size_t)(b * T_ + i)) * 2 + cell) * H_ + n] = f2bf(h2);
}

// ---------------------------------------------------------------------------
// In-place row log-softmax over V=10000, one block per row.
__global__ __launch_bounds__(256) void softmax_k(float* __restrict__ out) {
    __shared__ float buf[V_];
    __shared__ float red[4];
    int r = blockIdx.x;
    float* row = out + (size_t)r * V_;
    int tid = threadIdx.x;
    float lmax = -1e30f;
    for (int t = tid; t < V_; t += 256) {
        float v = row[t];
        buf[t] = v;
        lmax = fmaxf(lmax, v);
    }
#pragma unroll
    for (int o = 32; o; o >>= 1) lmax = fmaxf(lmax, __shfl_xor(lmax, o));
    if ((tid & 63) == 0) red[tid >> 6] = lmax;
    __syncthreads();
    float gmax = fmaxf(fmaxf(red[0], red[1]), fmaxf(red[2], red[3]));
    float ls = 0.f;
    for (int t = tid; t < V_; t += 256) ls += __expf(buf[t] - gmax);
#pragma unroll
    for (int o = 32; o; o >>= 1) ls += __shfl_xor(ls, o);
    __syncthreads();
    if ((tid & 63) == 0) red[tid >> 6] = ls;
    __syncthreads();
    float lse = gmax + __logf(red[0] + red[1] + red[2] + red[3]);
    for (int t = tid; t < V_; t += 256) row[t] = buf[t] - lse;
}

// ---------------------------------------------------------------------------
extern "C" void kernel_launch(void* const* d_in, const int* in_sizes, int n_in,
                              void* d_out, int out_size, void* d_ws, size_t ws_size,
                              hipStream_t stream) {
    const int* word_idx = (const int*)d_in[0];
    const int* father_idx = (const int*)d_in[1];
    const float* fc_feats = (const float*)d_in[2];
    const float* embed = (const float*)d_in[3];
    const float* fc_w = (const float*)d_in[4];
    const float* fc_b = (const float*)d_in[5];
    const float* a_wih = (const float*)d_in[6];
    const float* a_whh = (const float*)d_in[7];
    const float* a_bih = (const float*)d_in[8];
    const float* a_bhh = (const float*)d_in[9];
    const float* f_wih = (const float*)d_in[10];
    const float* f_whh = (const float*)d_in[11];
    const float* f_bih = (const float*)d_in[12];
    const float* f_bhh = (const float*)d_in[13];
    const float* pred_w = (const float*)d_in[14];
    const float* pred_b = (const float*)d_in[15];
    const float* logit_w = (const float*)d_in[16];
    const float* logit_b = (const float*)d_in[17];
    float* out = (float*)d_out;

    char* ws = (char*)d_ws;
    size_t off = 0;
    auto alloc = [&](size_t bytes) {
        void* p = ws + off;
        off += (bytes + 255) & ~(size_t)255;
        return p;
    };
    short* a_wih_h   = (short*)alloc((size_t)G_ * E_ * 2);
    short* f_wih_h   = (short*)alloc((size_t)G_ * E_ * 2);
    short* a_whh_h   = (short*)alloc((size_t)G_ * H_ * 2);
    short* f_whh_h   = (short*)alloc((size_t)G_ * H_ * 2);
    short* fc_w_h    = (short*)alloc((size_t)E_ * F_ * 2);
    short* pred_w_h  = (short*)alloc((size_t)H_ * 2 * H_ * 2);
    short* logit_w_h = (short*)alloc((size_t)V_ * H_ * 2);
    short* fc_feats_h= (short*)alloc((size_t)B_ * F_ * 2);
    float* bias_a    = (float*)alloc((size_t)G_ * 4);
    float* bias_f    = (float*)alloc((size_t)G_ * 4);
    short* XaIn      = (short*)alloc((size_t)B_ * T_ * E_ * 2);
    short* XfIn      = (short*)alloc((size_t)B_ * T_ * E_ * 2);
    short* XaP       = (short*)alloc((size_t)B_ * T_ * G_ * 2);
    short* XfP       = (short*)alloc((size_t)B_ * T_ * G_ * 2);
    short* H_all     = (short*)alloc((size_t)B_ * T_ * 2 * H_ * 2);
    float* cS        = (float*)alloc((size_t)B_ * T_ * H_ * 4);
    float* bcS       = (float*)alloc((size_t)B_ * T_ * H_ * 4);
    short* OUTb      = (short*)alloc((size_t)B_ * T_ * H_ * 2);
    if (off > ws_size) return;  // ~109 MB needed; leaves output poisoned -> loud failure

    // Phase 0: dtype converts + combined biases
    convert_k<<<512, 256, 0, stream>>>(a_wih, a_wih_h, G_ * E_);
    convert_k<<<512, 256, 0, stream>>>(f_wih, f_wih_h, G_ * E_);
    convert_k<<<512, 256, 0, stream>>>(a_whh, a_whh_h, G_ * H_);
    convert_k<<<512, 256, 0, stream>>>(f_whh, f_whh_h, G_ * H_);
    convert_k<<<512, 256, 0, stream>>>(fc_w, fc_w_h, E_ * F_);
    convert_k<<<512, 256, 0, stream>>>(pred_w, pred_w_h, H_ * 2 * H_);
    convert_k<<<1024, 256, 0, stream>>>(logit_w, logit_w_h, V_ * H_);
    convert_k<<<512, 256, 0, stream>>>(fc_feats, fc_feats_h, B_ * F_);
    bias2_k<<<16, 256, 0, stream>>>(a_bih, a_bhh, bias_a, f_bih, f_bhh, bias_f);

    // Phase 1: x_a0 = fc_feats @ fc_w.T + fc_b  -> bf16 rows (b, i=0) of XaIn
    gemm_bt<1, 0><<<dim3(4, 1), 256, 0, stream>>>(fc_feats_h, F_, fc_w_h, fc_b,
                                                  XaIn, T_ * E_, B_, E_, F_);
    // gather embeddings for all other rows
    gather_k<<<B_ * T_, 256, 0, stream>>>(word_idx, father_idx, embed, XaIn, XfIn);
    // batched input projections (bias folded in): XP = XIn @ wih.T + (bih+bhh)
    gemm_bt<1, 0><<<dim3(16, 40), 256, 0, stream>>>(XaIn, E_, a_wih_h, bias_a,
                                                    XaP, G_, B_ * T_, G_, E_);
    gemm_bt<1, 0><<<dim3(16, 40), 256, 0, stream>>>(XfIn, E_, f_wih_h, bias_f,
                                                    XfP, G_, B_ * T_, G_, E_);

    // Phase 2: recurrence — 40 flat-latency step launches; launch boundary = sync
    for (int i = 0; i < T_; i++) {
        int reset = (i == 0) || (((i - 1) % 3) == 0) ? 1 : 0;
        step3_k<<<512, 256, 0, stream>>>(XaP, XfP, a_whh_h, f_whh_h, H_all, cS, bcS,
                                         father_idx, i, reset);
    }

    // Phase 3: pred head, logits, log-softmax
    gemm_bt<1, 1><<<dim3(4, 40), 256, 0, stream>>>(H_all, 2 * H_, pred_w_h, pred_b,
                                                   OUTb, H_, B_ * T_, H_, 2 * H_);
    gemm_bt<0, 0><<<dim3(79, 40), 256, 0, stream>>>(OUTb, H_, logit_w_h, logit_b,
                                                    out, V_, B_ * T_, V_, H_);
    softmax_k<<<B_ * T_, 256, 0, stream>>>(out);
}